// Round 7
// baseline (1812.101 us; speedup 1.0000x reference)
//
#include <hip/hip_runtime.h>
#include <hip/hip_bf16.h>

#define NPT   16384
#define NQ    512
#define NS    32
#define BATCH 8
#define NRG   32          // pruning regions per batch (2 per wave)
#define RPTS  512         // points per region
#define PPT   16          // points per thread (sort kernel loops)

// ---------------------------------------------------------------------------
// DPP helper on a 64-bit value (two 32-bit halves), invalid lanes -> 0.
// Keys are (dist_bits<<32)|~orig_idx: always positive/finite as f64 patterns,
// so v_max_f64 == exact u64 max (positive doubles: value order == bit order).
// ---------------------------------------------------------------------------
template <int CTRL>
__device__ inline double dpp_f64(double x)
{
    const unsigned long long u = (unsigned long long)__double_as_longlong(x);
    int lo = (int)(unsigned)u;
    int hi = (int)(unsigned)(u >> 32);
    lo = __builtin_amdgcn_update_dpp(0, lo, CTRL, 0xf, 0xf, true);
    hi = __builtin_amdgcn_update_dpp(0, hi, CTRL, 0xf, 0xf, true);
    return __longlong_as_double(
        (long long)(((unsigned long long)(unsigned)hi << 32) | (unsigned)lo));
}

__device__ inline unsigned long long d2u(double d)
{
    return (unsigned long long)__double_as_longlong(d);
}

__device__ inline float rfl_f(float v)
{
    return __uint_as_float(
        (unsigned)__builtin_amdgcn_readfirstlane((int)__float_as_uint(v)));
}

// full-wave u64 max via 6 DPP stages; returns wave max broadcast through
// readlane(63) as an SGPR-uniform value.
__device__ inline unsigned long long wave_max_u64(unsigned long long k)
{
    double kd = __longlong_as_double((long long)k);
    kd = fmax(kd, dpp_f64<0x111>(kd));   // row_shr:1
    kd = fmax(kd, dpp_f64<0x112>(kd));   // row_shr:2
    kd = fmax(kd, dpp_f64<0x114>(kd));   // row_shr:4
    kd = fmax(kd, dpp_f64<0x118>(kd));   // row_shr:8
    kd = fmax(kd, dpp_f64<0x142>(kd));   // row_bcast:15
    kd = fmax(kd, dpp_f64<0x143>(kd));   // row_bcast:31
    const unsigned long long u = d2u(kd);
    const int klo = __builtin_amdgcn_readlane((int)(unsigned)u, 63);
    const int khi = __builtin_amdgcn_readlane((int)(unsigned)(u >> 32), 63);
    return ((unsigned long long)(unsigned)khi << 32) | (unsigned)klo;
}

// ---------------------------------------------------------------------------
// Kernel 0: Morton grid sort (8x8x8 = 512 cells), one block per batch.
// Writes sorted SoA copies (exact fp32 copies) + original indices to ws.
// Intra-cell order is nondeterministic (LDS atomics) — harmless: all
// downstream math keys on the ORIGINAL index.
// ---------------------------------------------------------------------------
__device__ inline int spread3(int v)
{
    return (v & 1) | ((v & 2) << 2) | ((v & 4) << 4);
}

__global__ __launch_bounds__(1024) void sort_kernel(
    const float* __restrict__ xyz,
    float* __restrict__ sx, float* __restrict__ sy, float* __restrict__ sz,
    int* __restrict__ sorig)
{
    const int b = blockIdx.x;
    const int t = threadIdx.x;
    const float* xb = xyz + (size_t)b * NPT * 3;

    __shared__ unsigned hist[512];
    __shared__ unsigned cur[512];

    if (t < 512) hist[t] = 0;
    __syncthreads();

    for (int j = 0; j < PPT; ++j) {
        const int p = j * 1024 + t;
        const float x = xb[p * 3 + 0], y = xb[p * 3 + 1], z = xb[p * 3 + 2];
        int ix = (int)(x * 8.0f), iy = (int)(y * 8.0f), iz = (int)(z * 8.0f);
        ix = min(max(ix, 0), 7); iy = min(max(iy, 0), 7); iz = min(max(iz, 0), 7);
        const int cell = spread3(ix) | (spread3(iy) << 1) | (spread3(iz) << 2);
        atomicAdd(&hist[cell], 1u);
    }
    __syncthreads();

    const unsigned cnt = (t < 512) ? hist[t] : 0;
    for (int off = 1; off < 512; off <<= 1) {
        unsigned u = 0;
        if (t < 512 && t >= off) u = hist[t - off];
        __syncthreads();
        if (t < 512) hist[t] += u;
        __syncthreads();
    }
    if (t < 512) cur[t] = hist[t] - cnt;   // exclusive start offset
    __syncthreads();

    float* sxb = sx + (size_t)b * NPT;
    float* syb = sy + (size_t)b * NPT;
    float* szb = sz + (size_t)b * NPT;
    int*   sob = sorig + (size_t)b * NPT;

    for (int j = 0; j < PPT; ++j) {
        const int p = j * 1024 + t;
        const float x = xb[p * 3 + 0], y = xb[p * 3 + 1], z = xb[p * 3 + 2];
        int ix = (int)(x * 8.0f), iy = (int)(y * 8.0f), iz = (int)(z * 8.0f);
        ix = min(max(ix, 0), 7); iy = min(max(iy, 0), 7); iz = min(max(iz, 0), 7);
        const int cell = spread3(ix) | (spread3(iy) << 1) | (spread3(iz) << 2);
        const unsigned pos = atomicAdd(&cur[cell], 1u);
        sxb[pos] = x; syb[pos] = y; szb[pos] = z; sob[pos] = p;
    }
}

// ---------------------------------------------------------------------------
// Kernel 1: FPS, one block per batch, 1024 threads. 32 pruning regions of
// 512 spatially-sorted points (2 regions per wave); coords/indices/dists all
// in REGISTERS (16 pts/thread). Region skips a step iff
// mindist^2(pick, bbox)*margin >= its cached max-dist -> provably no d
// changes, cached candidate stays exact. NO global memory ops inside the
// step loop: picks buffered in LDS, winner coords pass through LDS slots,
// bboxes/cached keys in SGPRs. Tail: wave 0 reduces 32 slots via DPP.
// ---------------------------------------------------------------------------
__global__ __launch_bounds__(1024)
void fps_kernel(const float* __restrict__ xyz,
                const float* __restrict__ sx, const float* __restrict__ sy,
                const float* __restrict__ sz, const int* __restrict__ sorig,
                float* __restrict__ new_xyz)
{
#pragma clang fp contract(off)
    const int b    = blockIdx.x;
    const int t    = threadIdx.x;
    const int w    = t >> 6;
    const int lane = t & 63;

    const float* xb  = xyz + (size_t)b * NPT * 3;
    const float* sxb = sx + (size_t)b * NPT;
    const float* syb = sy + (size_t)b * NPT;
    const float* szb = sz + (size_t)b * NPT;
    const int*   sob = sorig + (size_t)b * NPT;

    __shared__ unsigned long long kslot[NRG];
    __shared__ float cxs[NRG], cys[NRG], czs[NRG];
    __shared__ float picks[NQ * 3];
    __shared__ float bcv[3];

    float X[16], Y[16], Z[16], D[16];
    unsigned O[16];
    float bb0[2], bb1[2], bb2[2], bb3[2], bb4[2], bb5[2];  // per-region bbox (SGPR)
    unsigned long long kc[2];

    const float INF = __int_as_float(0x7f800000);

    // ---- init: load 2 regions x 8 pts into registers, build bboxes --------
#pragma unroll
    for (int r = 0; r < 2; ++r) {
        const int base = (2 * w + r) * RPTS + lane * 8;
        const float4* fx = (const float4*)(sxb + base);
        const float4* fy = (const float4*)(syb + base);
        const float4* fz = (const float4*)(szb + base);
        const int4*   fo = (const int4*)(sob + base);
        const float4 x0 = fx[0], x1 = fx[1];
        const float4 y0 = fy[0], y1 = fy[1];
        const float4 z0 = fz[0], z1 = fz[1];
        const int4   o0 = fo[0], o1 = fo[1];
        X[r*8+0]=x0.x; X[r*8+1]=x0.y; X[r*8+2]=x0.z; X[r*8+3]=x0.w;
        X[r*8+4]=x1.x; X[r*8+5]=x1.y; X[r*8+6]=x1.z; X[r*8+7]=x1.w;
        Y[r*8+0]=y0.x; Y[r*8+1]=y0.y; Y[r*8+2]=y0.z; Y[r*8+3]=y0.w;
        Y[r*8+4]=y1.x; Y[r*8+5]=y1.y; Y[r*8+6]=y1.z; Y[r*8+7]=y1.w;
        Z[r*8+0]=z0.x; Z[r*8+1]=z0.y; Z[r*8+2]=z0.z; Z[r*8+3]=z0.w;
        Z[r*8+4]=z1.x; Z[r*8+5]=z1.y; Z[r*8+6]=z1.z; Z[r*8+7]=z1.w;
        O[r*8+0]=(unsigned)o0.x; O[r*8+1]=(unsigned)o0.y;
        O[r*8+2]=(unsigned)o0.z; O[r*8+3]=(unsigned)o0.w;
        O[r*8+4]=(unsigned)o1.x; O[r*8+5]=(unsigned)o1.y;
        O[r*8+6]=(unsigned)o1.z; O[r*8+7]=(unsigned)o1.w;

        float mnx = INF, mxx = -INF, mny = INF, mxy = -INF, mnz = INF, mxz = -INF;
#pragma unroll
        for (int j = 0; j < 8; ++j) {
            mnx = fminf(mnx, X[r*8+j]); mxx = fmaxf(mxx, X[r*8+j]);
            mny = fminf(mny, Y[r*8+j]); mxy = fmaxf(mxy, Y[r*8+j]);
            mnz = fminf(mnz, Z[r*8+j]); mxz = fmaxf(mxz, Z[r*8+j]);
        }
#pragma unroll
        for (int off = 1; off < 64; off <<= 1) {
            mnx = fminf(mnx, __shfl_xor(mnx, off, 64));
            mxx = fmaxf(mxx, __shfl_xor(mxx, off, 64));
            mny = fminf(mny, __shfl_xor(mny, off, 64));
            mxy = fmaxf(mxy, __shfl_xor(mxy, off, 64));
            mnz = fminf(mnz, __shfl_xor(mnz, off, 64));
            mxz = fmaxf(mxz, __shfl_xor(mxz, off, 64));
        }
        bb0[r] = rfl_f(mnx); bb1[r] = rfl_f(mxx);
        bb2[r] = rfl_f(mny); bb3[r] = rfl_f(mxy);
        bb4[r] = rfl_f(mnz); bb5[r] = rfl_f(mxz);
        kc[r]  = (unsigned long long)0x7f800000u << 32;   // ub = +inf
    }
#pragma unroll
    for (int j = 0; j < 16; ++j) D[j] = INF;

    float px = xb[0], py = xb[1], pz = xb[2];
    if (t == 0) { picks[0] = px; picks[1] = py; picks[2] = pz; }
    __syncthreads();

    for (int s = 1; s < NQ; ++s) {
        // ---- per-region: skip test, then in-register update + reduce ------
#pragma unroll
        for (int r = 0; r < 2; ++r) {
            const float ub = __uint_as_float((unsigned)(kc[r] >> 32));
            const float ddx = fmaxf(fmaxf(bb0[r] - px, px - bb1[r]), 0.0f);
            const float ddy = fmaxf(fmaxf(bb2[r] - py, py - bb3[r]), 0.0f);
            const float ddz = fmaxf(fmaxf(bb4[r] - pz, pz - bb5[r]), 0.0f);
            const float m2 = ddx * ddx + ddy * ddy + ddz * ddz;
            if (!(m2 >= ub * 1.00002f)) {       // wave-uniform branch
                unsigned long long kbest = 0;
                float bx = 0.f, by = 0.f, bz = 0.f;
#pragma unroll
                for (int j = 0; j < 8; ++j) {
                    const int jj = r * 8 + j;
                    const float dx = __fsub_rn(X[jj], px);
                    const float dy = __fsub_rn(Y[jj], py);
                    const float dz = __fsub_rn(Z[jj], pz);
                    const float d2 = __fadd_rn(
                        __fadd_rn(__fmul_rn(dx, dx), __fmul_rn(dy, dy)),
                        __fmul_rn(dz, dz));
                    const float dn = fminf(D[jj], d2);
                    D[jj] = dn;
                    const unsigned long long key =
                        ((unsigned long long)__float_as_uint(dn) << 32) |
                        (unsigned)(~O[jj]);
                    if (key > kbest) { kbest = key; bx = X[jj]; by = Y[jj]; bz = Z[jj]; }
                }
                const unsigned long long kmax = wave_max_u64(kbest);
                kc[r] = kmax;
                const unsigned long long em = __ballot(kbest == kmax);
                if (lane == __ffsll(em) - 1) {   // unique winner (keys unique)
                    const int reg = 2 * w + r;
                    kslot[reg] = kmax;
                    cxs[reg] = bx; cys[reg] = by; czs[reg] = bz;
                }
            }
        }
        __syncthreads();

        // ---- wave 0: reduce the 32 slots, publish pick --------------------
        if (w == 0) {
            const int slot = lane & 31;
            const unsigned long long k = kslot[slot];
            const unsigned long long kmax = wave_max_u64(k);
            const unsigned long long em = __ballot(k == kmax);
            if (lane == __ffsll(em) - 1) {
                const float vx = cxs[slot], vy = cys[slot], vz = czs[slot];
                bcv[0] = vx; bcv[1] = vy; bcv[2] = vz;
                picks[3 * s + 0] = vx; picks[3 * s + 1] = vy; picks[3 * s + 2] = vz;
            }
        }
        __syncthreads();

        px = bcv[0]; py = bcv[1]; pz = bcv[2];
    }

    // ---- bulk write of all picks -----------------------------------------
    for (int i = t; i < NQ * 3; i += 1024)
        new_xyz[(size_t)b * NQ * 3 + i] = picks[i];
}

// ---------------------------------------------------------------------------
// Kernel 2: ball query. One wave per (b,s) query; ascending index scan with
// ballot + prefix popcount collects exactly the 32 smallest in-radius indices.
// ---------------------------------------------------------------------------
__global__ __launch_bounds__(256) void bq_kernel(const float* __restrict__ xyz,
                                                 const float* __restrict__ newxyz,
                                                 int* __restrict__ gidx)
{
    const int wid  = (blockIdx.x * 256 + threadIdx.x) >> 6;  // 0..4095
    const int lane = threadIdx.x & 63;
    const int b    = wid >> 9;
    const float* xb = xyz + (size_t)b * NPT * 3;

    const float qx = newxyz[wid * 3 + 0];
    const float qy = newxyz[wid * 3 + 1];
    const float qz = newxyz[wid * 3 + 2];
    int* out = gidx + (size_t)wid * NS;

    const float R2 = 0.04f;   // f32(0.2*0.2 in f64); NOT 0.2f*0.2f (1 ulp higher)
    int cnt = 0, first = -1;

    for (int base = 0; base < NPT; base += 64) {
        const int p = base + lane;
        const float dx = __fsub_rn(xb[p * 3 + 0], qx);
        const float dy = __fsub_rn(xb[p * 3 + 1], qy);
        const float dz = __fsub_rn(xb[p * 3 + 2], qz);
        const float d  = __fadd_rn(__fadd_rn(__fmul_rn(dx, dx), __fmul_rn(dy, dy)),
                                   __fmul_rn(dz, dz));
        const bool in = (d <= R2);
        const unsigned long long m = __ballot(in);
        if (first < 0 && m) first = base + (__ffsll((unsigned long long)m) - 1);
        if (in) {
            const int pos = cnt + __popcll(m & ((1ull << lane) - 1ull));
            if (pos < NS) out[pos] = p;
        }
        cnt += __popcll(m);
        if (cnt >= NS) break;
    }
    if (cnt < NS) {
        const int f = (cnt > 0) ? first : (NPT - 1);
        for (int j = cnt + lane; j < NS; j += 64) out[j] = f;
    }
}

// ---------------------------------------------------------------------------
// Kernel 3: gather + 3-layer MLP (BN folded) + max over the 32 samples.
// One block per (b,s). Weights staged per-layer in a shared 34.8KB region.
// Channel layout permuted: [feat(64) | xyz-diff(3) | pad] for aligned float4.
// ---------------------------------------------------------------------------
template <int OP>
__device__ inline void mlp_layer(const float* __restrict__ inb,
                                 const float* __restrict__ wbuf,
                                 const float* __restrict__ scp,
                                 const float* __restrict__ bip,
                                 float* __restrict__ outb, int nchunk, int t)
{
    const int ko = t & 15;
    const int og = t >> 4;
    const int o0 = og * OP;
    float acc0[OP], acc1[OP];
#pragma unroll
    for (int j = 0; j < OP; ++j) { acc0[j] = 0.f; acc1[j] = 0.f; }

    for (int cc = 0; cc < nchunk; ++cc) {
        const int c = cc * 4;
        const float4 xa = *(const float4*)(inb + ko * 68 + c);
        const float4 xb = *(const float4*)(inb + (ko + 16) * 68 + c);
#pragma unroll
        for (int j = 0; j < OP; ++j) {
            const float4 w = *(const float4*)(wbuf + (o0 + j) * 68 + c);
            acc0[j] += xa.x * w.x + xa.y * w.y + xa.z * w.z + xa.w * w.w;
            acc1[j] += xb.x * w.x + xb.y * w.y + xb.z * w.z + xb.w * w.w;
        }
    }
#pragma unroll
    for (int j = 0; j < OP; ++j) {
        const float sv = scp[o0 + j], bv = bip[o0 + j];
        acc0[j] = fmaxf(acc0[j] * sv + bv, 0.f);
        acc1[j] = fmaxf(acc1[j] * sv + bv, 0.f);
    }
#pragma unroll
    for (int jb = 0; jb < OP; jb += 4) {
        *(float4*)(outb + ko * 68 + o0 + jb) =
            make_float4(acc0[jb], acc0[jb + 1], acc0[jb + 2], acc0[jb + 3]);
        *(float4*)(outb + (ko + 16) * 68 + o0 + jb) =
            make_float4(acc1[jb], acc1[jb + 1], acc1[jb + 2], acc1[jb + 3]);
    }
}

__device__ inline void mlp_layer2(const float* __restrict__ inb,
                                  const float* __restrict__ wbuf,
                                  const float* __restrict__ scp,
                                  const float* __restrict__ bip,
                                  float* __restrict__ out, int b, int s, int t)
{
    const int ko = t & 15;
    const int og = t >> 4;
    const int o0 = og * 8;
    float acc0[8], acc1[8];
#pragma unroll
    for (int j = 0; j < 8; ++j) { acc0[j] = 0.f; acc1[j] = 0.f; }

    for (int cc = 0; cc < 16; ++cc) {
        const int c = cc * 4;
        const float4 xa = *(const float4*)(inb + ko * 68 + c);
        const float4 xb = *(const float4*)(inb + (ko + 16) * 68 + c);
#pragma unroll
        for (int j = 0; j < 8; ++j) {
            const float4 w = *(const float4*)(wbuf + (o0 + j) * 68 + c);
            acc0[j] += xa.x * w.x + xa.y * w.y + xa.z * w.z + xa.w * w.w;
            acc1[j] += xb.x * w.x + xb.y * w.y + xb.z * w.z + xb.w * w.w;
        }
    }
    float v[8];
#pragma unroll
    for (int j = 0; j < 8; ++j) {
        const float sv = scp[o0 + j], bv = bip[o0 + j];
        const float h0 = fmaxf(acc0[j] * sv + bv, 0.f);
        const float h1 = fmaxf(acc1[j] * sv + bv, 0.f);
        v[j] = fmaxf(h0, h1);
    }
#pragma unroll
    for (int m = 1; m <= 8; m <<= 1) {
#pragma unroll
        for (int j = 0; j < 8; ++j) v[j] = fmaxf(v[j], __shfl_xor(v[j], m, 64));
    }
    if (ko == 0) {
#pragma unroll
        for (int j = 0; j < 8; ++j)
            out[((size_t)b * 128 + o0 + j) * NQ + s] = v[j];
    }
}

__global__ __launch_bounds__(256) void mlp_kernel(
    const float* __restrict__ xyz, const float* __restrict__ feat,
    const float* __restrict__ newxyz, const int* __restrict__ gidx,
    const float* __restrict__ w0, const float* __restrict__ g0,
    const float* __restrict__ b0, const float* __restrict__ m0,
    const float* __restrict__ v0,
    const float* __restrict__ w1, const float* __restrict__ g1,
    const float* __restrict__ b1, const float* __restrict__ m1,
    const float* __restrict__ v1,
    const float* __restrict__ w2, const float* __restrict__ g2,
    const float* __restrict__ b2, const float* __restrict__ m2,
    const float* __restrict__ v2,
    float* __restrict__ out)
{
    __shared__ float wbuf[128 * 68];   // 34816 B
    __shared__ float bufA[32 * 68];    //  8704 B
    __shared__ float bufB[32 * 68];    //  8704 B
    __shared__ float sc[256], bi[256]; //  2048 B   -> total 54272 B

    const int t   = threadIdx.x;
    const int grp = blockIdx.x;       // 0..4095
    const int b   = grp >> 9;
    const int s   = grp & (NQ - 1);
    const int* gi = gidx + (size_t)grp * NS;

    // folded BN params for all three layers
    if (t < 64) {
        const float sv = g0[t] * rsqrtf(v0[t] + 1e-5f);
        sc[t] = sv; bi[t] = b0[t] - m0[t] * sv;
    } else if (t < 128) {
        const int j = t - 64;
        const float sv = g1[j] * rsqrtf(v1[j] + 1e-5f);
        sc[t] = sv; bi[t] = b1[j] - m1[j] * sv;
    } else {
        const int j = t - 128;
        const float sv = g2[j] * rsqrtf(v2[j] + 1e-5f);
        sc[t] = sv; bi[t] = b2[j] - m2[j] * sv;
    }

    // layer-0 weights, channel-permuted: [feat 0..63 | xyz 64..66 | 0]
    for (int i = t; i < 64 * 68; i += 256) {
        const int o = i / 68, c = i - o * 68;
        float v;
        if (c < 64)       v = w0[o * 67 + 3 + c];
        else if (c < 67)  v = w0[o * 67 + (c - 64)];
        else              v = 0.f;
        wbuf[i] = v;
    }

    // gather x into bufA: feat then xyz-diff
    {
        const int k = t >> 3, f = t & 7;
        const int p = gi[k];
        const float* fr = feat + ((size_t)b * NPT + p) * 64 + f * 8;
        const float4 a0 = *(const float4*)fr;
        const float4 a1 = *(const float4*)(fr + 4);
        *(float4*)(bufA + k * 68 + f * 8)     = a0;
        *(float4*)(bufA + k * 68 + f * 8 + 4) = a1;
        if (f == 0) {
            const float qx = newxyz[grp * 3 + 0];
            const float qy = newxyz[grp * 3 + 1];
            const float qz = newxyz[grp * 3 + 2];
            const float* xp = xyz + ((size_t)b * NPT + p) * 3;
            bufA[k * 68 + 64] = xp[0] - qx;
            bufA[k * 68 + 65] = xp[1] - qy;
            bufA[k * 68 + 66] = xp[2] - qz;
            bufA[k * 68 + 67] = 0.f;
        }
    }
    __syncthreads();

    mlp_layer<4>(bufA, wbuf, sc, bi, bufB, 17, t);
    __syncthreads();

    for (int i = t; i < 64 * 68; i += 256) {
        const int o = i / 68, c = i - o * 68;
        wbuf[i] = (c < 64) ? w1[o * 64 + c] : 0.f;
    }
    __syncthreads();

    mlp_layer<4>(bufB, wbuf, sc + 64, bi + 64, bufA, 16, t);
    __syncthreads();

    for (int i = t; i < 128 * 68; i += 256) {
        const int o = i / 68, c = i - o * 68;
        wbuf[i] = (c < 64) ? w2[o * 64 + c] : 0.f;
    }
    __syncthreads();

    mlp_layer2(bufA, wbuf, sc + 128, bi + 128, out, b, s, t);
}

// ---------------------------------------------------------------------------
extern "C" void kernel_launch(void* const* d_in, const int* in_sizes, int n_in,
                              void* d_out, int out_size, void* d_ws, size_t ws_size,
                              hipStream_t stream)
{
    const float* xyz  = (const float*)d_in[0];
    const float* feat = (const float*)d_in[1];
    const float* w0 = (const float*)d_in[2];
    const float* g0 = (const float*)d_in[3];
    const float* b0 = (const float*)d_in[4];
    const float* m0 = (const float*)d_in[5];
    const float* v0 = (const float*)d_in[6];
    const float* w1 = (const float*)d_in[7];
    const float* g1 = (const float*)d_in[8];
    const float* b1 = (const float*)d_in[9];
    const float* m1 = (const float*)d_in[10];
    const float* v1 = (const float*)d_in[11];
    const float* w2 = (const float*)d_in[12];
    const float* g2 = (const float*)d_in[13];
    const float* b2 = (const float*)d_in[14];
    const float* m2 = (const float*)d_in[15];
    const float* v2 = (const float*)d_in[16];

    float* out      = (float*)d_out;
    float* new_xyz  = out;                      // 8*512*3 = 12288 floats
    float* out_feat = out + BATCH * NQ * 3;     // 8*128*512 floats

    // workspace layout
    int*   gidx  = (int*)d_ws;                                  // 524288 B
    float* sxp   = (float*)((char*)d_ws + 524288);              // 512 KB
    float* syp   = sxp + BATCH * NPT;                           // 512 KB
    float* szp   = syp + BATCH * NPT;                           // 512 KB
    int*   sorig = (int*)(szp + BATCH * NPT);                   // 512 KB

    sort_kernel<<<BATCH, 1024, 0, stream>>>(xyz, sxp, syp, szp, sorig);
    fps_kernel<<<BATCH, 1024, 0, stream>>>(xyz, sxp, syp, szp, sorig, new_xyz);
    bq_kernel<<<(BATCH * NQ * 64) / 256, 256, 0, stream>>>(xyz, new_xyz, gidx);
    mlp_kernel<<<BATCH * NQ, 256, 0, stream>>>(xyz, feat, new_xyz, gidx,
                                               w0, g0, b0, m0, v0,
                                               w1, g1, b1, m1, v1,
                                               w2, g2, b2, m2, v2,
                                               out_feat);
}

// Round 8
// 1279.442 us; speedup vs baseline: 1.4163x; 1.4163x over previous
//
#include <hip/hip_runtime.h>
#include <hip/hip_bf16.h>

#define NPT   16384
#define NQ    512
#define NS    32
#define BATCH 8
#define NRG   32          // pruning regions per batch (2 per wave)
#define RPTS  512         // points per region
#define PPT   16          // points per thread (sort kernel loops)

// ---------------------------------------------------------------------------
// DPP helper on a 64-bit value (two 32-bit halves), invalid lanes -> 0.
// Keys are (dist_bits<<32)|~orig_idx: always positive/finite as f64 patterns,
// so v_max_f64 == exact u64 max (positive doubles: value order == bit order).
// ---------------------------------------------------------------------------
template <int CTRL>
__device__ inline double dpp_f64(double x)
{
    const unsigned long long u = (unsigned long long)__double_as_longlong(x);
    int lo = (int)(unsigned)u;
    int hi = (int)(unsigned)(u >> 32);
    lo = __builtin_amdgcn_update_dpp(0, lo, CTRL, 0xf, 0xf, true);
    hi = __builtin_amdgcn_update_dpp(0, hi, CTRL, 0xf, 0xf, true);
    return __longlong_as_double(
        (long long)(((unsigned long long)(unsigned)hi << 32) | (unsigned)lo));
}

__device__ inline unsigned long long d2u(double d)
{
    return (unsigned long long)__double_as_longlong(d);
}

__device__ inline float rfl_f(float v)
{
    return __uint_as_float(
        (unsigned)__builtin_amdgcn_readfirstlane((int)__float_as_uint(v)));
}

__device__ inline float readlane_f(float v, int l)
{
    return __uint_as_float(
        (unsigned)__builtin_amdgcn_readlane((int)__float_as_uint(v), l));
}

// full-wave u64 max via 6 DPP stages, broadcast to all lanes as uniform.
__device__ inline unsigned long long wave_max_u64(unsigned long long k)
{
    double kd = __longlong_as_double((long long)k);
    kd = fmax(kd, dpp_f64<0x111>(kd));   // row_shr:1
    kd = fmax(kd, dpp_f64<0x112>(kd));   // row_shr:2
    kd = fmax(kd, dpp_f64<0x114>(kd));   // row_shr:4
    kd = fmax(kd, dpp_f64<0x118>(kd));   // row_shr:8
    kd = fmax(kd, dpp_f64<0x142>(kd));   // row_bcast:15
    kd = fmax(kd, dpp_f64<0x143>(kd));   // row_bcast:31
    const unsigned long long u = d2u(kd);
    const int klo = __builtin_amdgcn_readlane((int)(unsigned)u, 63);
    const int khi = __builtin_amdgcn_readlane((int)(unsigned)(u >> 32), 63);
    return ((unsigned long long)(unsigned)khi << 32) | (unsigned)klo;
}

// ---------------------------------------------------------------------------
// Kernel 0: Morton grid sort (8x8x8 = 512 cells), one block per batch.
// Writes sorted SoA copies (exact fp32 copies) + original indices to ws.
// Intra-cell order nondeterministic (LDS atomics) — harmless: downstream
// keys use the ORIGINAL index.
// ---------------------------------------------------------------------------
__device__ inline int spread3(int v)
{
    return (v & 1) | ((v & 2) << 2) | ((v & 4) << 4);
}

__global__ __launch_bounds__(1024) void sort_kernel(
    const float* __restrict__ xyz,
    float* __restrict__ sx, float* __restrict__ sy, float* __restrict__ sz,
    int* __restrict__ sorig)
{
    const int b = blockIdx.x;
    const int t = threadIdx.x;
    const float* xb = xyz + (size_t)b * NPT * 3;

    __shared__ unsigned hist[512];
    __shared__ unsigned cur[512];

    if (t < 512) hist[t] = 0;
    __syncthreads();

    for (int j = 0; j < PPT; ++j) {
        const int p = j * 1024 + t;
        const float x = xb[p * 3 + 0], y = xb[p * 3 + 1], z = xb[p * 3 + 2];
        int ix = (int)(x * 8.0f), iy = (int)(y * 8.0f), iz = (int)(z * 8.0f);
        ix = min(max(ix, 0), 7); iy = min(max(iy, 0), 7); iz = min(max(iz, 0), 7);
        const int cell = spread3(ix) | (spread3(iy) << 1) | (spread3(iz) << 2);
        atomicAdd(&hist[cell], 1u);
    }
    __syncthreads();

    const unsigned cnt = (t < 512) ? hist[t] : 0;
    for (int off = 1; off < 512; off <<= 1) {
        unsigned u = 0;
        if (t < 512 && t >= off) u = hist[t - off];
        __syncthreads();
        if (t < 512) hist[t] += u;
        __syncthreads();
    }
    if (t < 512) cur[t] = hist[t] - cnt;   // exclusive start offset
    __syncthreads();

    float* sxb = sx + (size_t)b * NPT;
    float* syb = sy + (size_t)b * NPT;
    float* szb = sz + (size_t)b * NPT;
    int*   sob = sorig + (size_t)b * NPT;

    for (int j = 0; j < PPT; ++j) {
        const int p = j * 1024 + t;
        const float x = xb[p * 3 + 0], y = xb[p * 3 + 1], z = xb[p * 3 + 2];
        int ix = (int)(x * 8.0f), iy = (int)(y * 8.0f), iz = (int)(z * 8.0f);
        ix = min(max(ix, 0), 7); iy = min(max(iy, 0), 7); iz = min(max(iz, 0), 7);
        const int cell = spread3(ix) | (spread3(iy) << 1) | (spread3(iz) << 2);
        const unsigned pos = atomicAdd(&cur[cell], 1u);
        sxb[pos] = x; syb[pos] = y; szb[pos] = z; sob[pos] = p;
    }
}

// ---------------------------------------------------------------------------
// Kernel 1: FPS, one block per batch, 1024 threads. 32 regions of 512
// sorted points (2 per wave). ONLY D[16] is loop-carried per-thread state;
// coords/orig-idx are re-loaded from the sorted SoA (L2) when a region is
// active. Region skips iff mindist^2(pick,bbox)*margin >= cached max-dist
// (provably no d changes -> cached candidate stays exact). ONE barrier per
// step: parity-buffered LDS slots republished unconditionally, then every
// wave does the lane-parallel 32-slot DPP combine. No global ops in-loop.
// ---------------------------------------------------------------------------
__global__ __launch_bounds__(1024)
void fps_kernel(const float* __restrict__ xyz,
                const float* __restrict__ sx, const float* __restrict__ sy,
                const float* __restrict__ sz, const int* __restrict__ sorig,
                float* __restrict__ new_xyz)
{
#pragma clang fp contract(off)
    const int b    = blockIdx.x;
    const int t    = threadIdx.x;
    const int w    = t >> 6;
    const int lane = t & 63;

    const float* xb  = xyz + (size_t)b * NPT * 3;
    const float* sxb = sx + (size_t)b * NPT;
    const float* syb = sy + (size_t)b * NPT;
    const float* szb = sz + (size_t)b * NPT;
    const int*   sob = sorig + (size_t)b * NPT;

    __shared__ unsigned long long kslot[2][NRG];
    __shared__ float cxs[2][NRG], cys[2][NRG], czs[2][NRG];
    __shared__ float picks[NQ * 3];

    float D[16];
    float bb0[2], bb1[2], bb2[2], bb3[2], bb4[2], bb5[2];  // bbox (uniform)
    unsigned long long kc[2];
    float ccx[2], ccy[2], ccz[2];                          // cached cand (uniform)

    const float INF = __int_as_float(0x7f800000);

    // ---- init: transient coord load to build region bboxes ----------------
#pragma unroll
    for (int r = 0; r < 2; ++r) {
        const int base = (2 * w + r) * RPTS + lane * 8;
        const float4* fx = (const float4*)(sxb + base);
        const float4* fy = (const float4*)(syb + base);
        const float4* fz = (const float4*)(szb + base);
        const float4 x0 = fx[0], x1 = fx[1];
        const float4 y0 = fy[0], y1 = fy[1];
        const float4 z0 = fz[0], z1 = fz[1];
        float mnx = fminf(fminf(fminf(x0.x, x0.y), fminf(x0.z, x0.w)),
                          fminf(fminf(x1.x, x1.y), fminf(x1.z, x1.w)));
        float mxx = fmaxf(fmaxf(fmaxf(x0.x, x0.y), fmaxf(x0.z, x0.w)),
                          fmaxf(fmaxf(x1.x, x1.y), fmaxf(x1.z, x1.w)));
        float mny = fminf(fminf(fminf(y0.x, y0.y), fminf(y0.z, y0.w)),
                          fminf(fminf(y1.x, y1.y), fminf(y1.z, y1.w)));
        float mxy = fmaxf(fmaxf(fmaxf(y0.x, y0.y), fmaxf(y0.z, y0.w)),
                          fmaxf(fmaxf(y1.x, y1.y), fmaxf(y1.z, y1.w)));
        float mnz = fminf(fminf(fminf(z0.x, z0.y), fminf(z0.z, z0.w)),
                          fminf(fminf(z1.x, z1.y), fminf(z1.z, z1.w)));
        float mxz = fmaxf(fmaxf(fmaxf(z0.x, z0.y), fmaxf(z0.z, z0.w)),
                          fmaxf(fmaxf(z1.x, z1.y), fmaxf(z1.z, z1.w)));
#pragma unroll
        for (int off = 1; off < 64; off <<= 1) {
            mnx = fminf(mnx, __shfl_xor(mnx, off, 64));
            mxx = fmaxf(mxx, __shfl_xor(mxx, off, 64));
            mny = fminf(mny, __shfl_xor(mny, off, 64));
            mxy = fmaxf(mxy, __shfl_xor(mxy, off, 64));
            mnz = fminf(mnz, __shfl_xor(mnz, off, 64));
            mxz = fmaxf(mxz, __shfl_xor(mxz, off, 64));
        }
        bb0[r] = rfl_f(mnx); bb1[r] = rfl_f(mxx);
        bb2[r] = rfl_f(mny); bb3[r] = rfl_f(mxy);
        bb4[r] = rfl_f(mnz); bb5[r] = rfl_f(mxz);
        kc[r]  = (unsigned long long)0x7f800000u << 32;   // ub = +inf
        ccx[r] = 0.f; ccy[r] = 0.f; ccz[r] = 0.f;
    }
#pragma unroll
    for (int j = 0; j < 16; ++j) D[j] = INF;

    float px = xb[0], py = xb[1], pz = xb[2];
    if (t == 0) { picks[0] = px; picks[1] = py; picks[2] = pz; }

    for (int s = 1; s < NQ; ++s) {
        const int par = s & 1;

        // ---- per-region: skip test, conditional reload + update -----------
#pragma unroll
        for (int r = 0; r < 2; ++r) {
            const int reg = 2 * w + r;
            const float ub = __uint_as_float((unsigned)(kc[r] >> 32));
            const float ddx = fmaxf(fmaxf(bb0[r] - px, px - bb1[r]), 0.0f);
            const float ddy = fmaxf(fmaxf(bb2[r] - py, py - bb3[r]), 0.0f);
            const float ddz = fmaxf(fmaxf(bb4[r] - pz, pz - bb5[r]), 0.0f);
            const float m2 = ddx * ddx + ddy * ddy + ddz * ddz;
            if (!(m2 >= ub * 1.00002f)) {       // wave-uniform branch
                const int base = reg * RPTS + lane * 8;
                const float4* fx = (const float4*)(sxb + base);
                const float4* fy = (const float4*)(syb + base);
                const float4* fz = (const float4*)(szb + base);
                const int4*   fo = (const int4*)(sob + base);
                const float4 x0 = fx[0], x1 = fx[1];
                const float4 y0 = fy[0], y1 = fy[1];
                const float4 z0 = fz[0], z1 = fz[1];
                const int4   o0 = fo[0], o1 = fo[1];
                const float xs[8] = {x0.x, x0.y, x0.z, x0.w, x1.x, x1.y, x1.z, x1.w};
                const float ys[8] = {y0.x, y0.y, y0.z, y0.w, y1.x, y1.y, y1.z, y1.w};
                const float zs[8] = {z0.x, z0.y, z0.z, z0.w, z1.x, z1.y, z1.z, z1.w};
                const unsigned os[8] = {(unsigned)o0.x, (unsigned)o0.y,
                                        (unsigned)o0.z, (unsigned)o0.w,
                                        (unsigned)o1.x, (unsigned)o1.y,
                                        (unsigned)o1.z, (unsigned)o1.w};
                unsigned long long kbest = 0;
                float bx = 0.f, by = 0.f, bz = 0.f;
#pragma unroll
                for (int j = 0; j < 8; ++j) {
                    const int jj = r * 8 + j;
                    const float dx = __fsub_rn(xs[j], px);
                    const float dy = __fsub_rn(ys[j], py);
                    const float dz = __fsub_rn(zs[j], pz);
                    const float d2 = __fadd_rn(
                        __fadd_rn(__fmul_rn(dx, dx), __fmul_rn(dy, dy)),
                        __fmul_rn(dz, dz));
                    const float dn = fminf(D[jj], d2);
                    D[jj] = dn;
                    const unsigned long long key =
                        ((unsigned long long)__float_as_uint(dn) << 32) |
                        (unsigned)(~os[j]);
                    if (key > kbest) { kbest = key; bx = xs[j]; by = ys[j]; bz = zs[j]; }
                }
                const unsigned long long kmax = wave_max_u64(kbest);
                kc[r] = kmax;
                const unsigned long long em = __ballot(kbest == kmax);
                const int wl = __ffsll(em) - 1;     // unique winner (keys unique)
                ccx[r] = readlane_f(bx, wl);
                ccy[r] = readlane_f(by, wl);
                ccz[r] = readlane_f(bz, wl);
            }
            // unconditional parity-slot publish (uniform values, 1 lane)
            if (lane == r) {
                kslot[par][reg] = kc[r];
                cxs[par][reg] = ccx[r];
                cys[par][reg] = ccy[r];
                czs[par][reg] = ccz[r];
            }
        }
        __syncthreads();

        // ---- lane-parallel combine over 32 slots (every wave) -------------
        const int slot = lane & 31;
        const unsigned long long k = kslot[par][slot];
        const float cxv = cxs[par][slot];
        const float cyv = cys[par][slot];
        const float czv = czs[par][slot];
        const unsigned long long kmax = wave_max_u64(k);
        const unsigned long long em = __ballot(k == kmax);
        const int wl = __ffsll(em) - 1;
        px = readlane_f(cxv, wl);
        py = readlane_f(cyv, wl);
        pz = readlane_f(czv, wl);

        if (t == 0) {
            picks[3 * s + 0] = px; picks[3 * s + 1] = py; picks[3 * s + 2] = pz;
        }
    }
    __syncthreads();

    // ---- bulk write of all picks -----------------------------------------
    for (int i = t; i < NQ * 3; i += 1024)
        new_xyz[(size_t)b * NQ * 3 + i] = picks[i];
}

// ---------------------------------------------------------------------------
// Kernel 2: ball query. One wave per (b,s) query; ascending index scan with
// ballot + prefix popcount collects exactly the 32 smallest in-radius indices.
// ---------------------------------------------------------------------------
__global__ __launch_bounds__(256) void bq_kernel(const float* __restrict__ xyz,
                                                 const float* __restrict__ newxyz,
                                                 int* __restrict__ gidx)
{
    const int wid  = (blockIdx.x * 256 + threadIdx.x) >> 6;  // 0..4095
    const int lane = threadIdx.x & 63;
    const int b    = wid >> 9;
    const float* xb = xyz + (size_t)b * NPT * 3;

    const float qx = newxyz[wid * 3 + 0];
    const float qy = newxyz[wid * 3 + 1];
    const float qz = newxyz[wid * 3 + 2];
    int* out = gidx + (size_t)wid * NS;

    const float R2 = 0.04f;   // f32(0.2*0.2 in f64); NOT 0.2f*0.2f (1 ulp higher)
    int cnt = 0, first = -1;

    for (int base = 0; base < NPT; base += 64) {
        const int p = base + lane;
        const float dx = __fsub_rn(xb[p * 3 + 0], qx);
        const float dy = __fsub_rn(xb[p * 3 + 1], qy);
        const float dz = __fsub_rn(xb[p * 3 + 2], qz);
        const float d  = __fadd_rn(__fadd_rn(__fmul_rn(dx, dx), __fmul_rn(dy, dy)),
                                   __fmul_rn(dz, dz));
        const bool in = (d <= R2);
        const unsigned long long m = __ballot(in);
        if (first < 0 && m) first = base + (__ffsll((unsigned long long)m) - 1);
        if (in) {
            const int pos = cnt + __popcll(m & ((1ull << lane) - 1ull));
            if (pos < NS) out[pos] = p;
        }
        cnt += __popcll(m);
        if (cnt >= NS) break;
    }
    if (cnt < NS) {
        const int f = (cnt > 0) ? first : (NPT - 1);
        for (int j = cnt + lane; j < NS; j += 64) out[j] = f;
    }
}

// ---------------------------------------------------------------------------
// Kernel 3: gather + 3-layer MLP (BN folded) + max over the 32 samples.
// One block per (b,s). Weights staged per-layer in a shared 34.8KB region.
// Channel layout permuted: [feat(64) | xyz-diff(3) | pad] for aligned float4.
// ---------------------------------------------------------------------------
template <int OP>
__device__ inline void mlp_layer(const float* __restrict__ inb,
                                 const float* __restrict__ wbuf,
                                 const float* __restrict__ scp,
                                 const float* __restrict__ bip,
                                 float* __restrict__ outb, int nchunk, int t)
{
    const int ko = t & 15;
    const int og = t >> 4;
    const int o0 = og * OP;
    float acc0[OP], acc1[OP];
#pragma unroll
    for (int j = 0; j < OP; ++j) { acc0[j] = 0.f; acc1[j] = 0.f; }

    for (int cc = 0; cc < nchunk; ++cc) {
        const int c = cc * 4;
        const float4 xa = *(const float4*)(inb + ko * 68 + c);
        const float4 xb = *(const float4*)(inb + (ko + 16) * 68 + c);
#pragma unroll
        for (int j = 0; j < OP; ++j) {
            const float4 w = *(const float4*)(wbuf + (o0 + j) * 68 + c);
            acc0[j] += xa.x * w.x + xa.y * w.y + xa.z * w.z + xa.w * w.w;
            acc1[j] += xb.x * w.x + xb.y * w.y + xb.z * w.z + xb.w * w.w;
        }
    }
#pragma unroll
    for (int j = 0; j < OP; ++j) {
        const float sv = scp[o0 + j], bv = bip[o0 + j];
        acc0[j] = fmaxf(acc0[j] * sv + bv, 0.f);
        acc1[j] = fmaxf(acc1[j] * sv + bv, 0.f);
    }
#pragma unroll
    for (int jb = 0; jb < OP; jb += 4) {
        *(float4*)(outb + ko * 68 + o0 + jb) =
            make_float4(acc0[jb], acc0[jb + 1], acc0[jb + 2], acc0[jb + 3]);
        *(float4*)(outb + (ko + 16) * 68 + o0 + jb) =
            make_float4(acc1[jb], acc1[jb + 1], acc1[jb + 2], acc1[jb + 3]);
    }
}

__device__ inline void mlp_layer2(const float* __restrict__ inb,
                                  const float* __restrict__ wbuf,
                                  const float* __restrict__ scp,
                                  const float* __restrict__ bip,
                                  float* __restrict__ out, int b, int s, int t)
{
    const int ko = t & 15;
    const int og = t >> 4;
    const int o0 = og * 8;
    float acc0[8], acc1[8];
#pragma unroll
    for (int j = 0; j < 8; ++j) { acc0[j] = 0.f; acc1[j] = 0.f; }

    for (int cc = 0; cc < 16; ++cc) {
        const int c = cc * 4;
        const float4 xa = *(const float4*)(inb + ko * 68 + c);
        const float4 xb = *(const float4*)(inb + (ko + 16) * 68 + c);
#pragma unroll
        for (int j = 0; j < 8; ++j) {
            const float4 w = *(const float4*)(wbuf + (o0 + j) * 68 + c);
            acc0[j] += xa.x * w.x + xa.y * w.y + xa.z * w.z + xa.w * w.w;
            acc1[j] += xb.x * w.x + xb.y * w.y + xb.z * w.z + xb.w * w.w;
        }
    }
    float v[8];
#pragma unroll
    for (int j = 0; j < 8; ++j) {
        const float sv = scp[o0 + j], bv = bip[o0 + j];
        const float h0 = fmaxf(acc0[j] * sv + bv, 0.f);
        const float h1 = fmaxf(acc1[j] * sv + bv, 0.f);
        v[j] = fmaxf(h0, h1);
    }
#pragma unroll
    for (int m = 1; m <= 8; m <<= 1) {
#pragma unroll
        for (int j = 0; j < 8; ++j) v[j] = fmaxf(v[j], __shfl_xor(v[j], m, 64));
    }
    if (ko == 0) {
#pragma unroll
        for (int j = 0; j < 8; ++j)
            out[((size_t)b * 128 + o0 + j) * NQ + s] = v[j];
    }
}

__global__ __launch_bounds__(256) void mlp_kernel(
    const float* __restrict__ xyz, const float* __restrict__ feat,
    const float* __restrict__ newxyz, const int* __restrict__ gidx,
    const float* __restrict__ w0, const float* __restrict__ g0,
    const float* __restrict__ b0, const float* __restrict__ m0,
    const float* __restrict__ v0,
    const float* __restrict__ w1, const float* __restrict__ g1,
    const float* __restrict__ b1, const float* __restrict__ m1,
    const float* __restrict__ v1,
    const float* __restrict__ w2, const float* __restrict__ g2,
    const float* __restrict__ b2, const float* __restrict__ m2,
    const float* __restrict__ v2,
    float* __restrict__ out)
{
    __shared__ float wbuf[128 * 68];   // 34816 B
    __shared__ float bufA[32 * 68];    //  8704 B
    __shared__ float bufB[32 * 68];    //  8704 B
    __shared__ float sc[256], bi[256]; //  2048 B   -> total 54272 B

    const int t   = threadIdx.x;
    const int grp = blockIdx.x;       // 0..4095
    const int b   = grp >> 9;
    const int s   = grp & (NQ - 1);
    const int* gi = gidx + (size_t)grp * NS;

    // folded BN params for all three layers
    if (t < 64) {
        const float sv = g0[t] * rsqrtf(v0[t] + 1e-5f);
        sc[t] = sv; bi[t] = b0[t] - m0[t] * sv;
    } else if (t < 128) {
        const int j = t - 64;
        const float sv = g1[j] * rsqrtf(v1[j] + 1e-5f);
        sc[t] = sv; bi[t] = b1[j] - m1[j] * sv;
    } else {
        const int j = t - 128;
        const float sv = g2[j] * rsqrtf(v2[j] + 1e-5f);
        sc[t] = sv; bi[t] = b2[j] - m2[j] * sv;
    }

    // layer-0 weights, channel-permuted: [feat 0..63 | xyz 64..66 | 0]
    for (int i = t; i < 64 * 68; i += 256) {
        const int o = i / 68, c = i - o * 68;
        float v;
        if (c < 64)       v = w0[o * 67 + 3 + c];
        else if (c < 67)  v = w0[o * 67 + (c - 64)];
        else              v = 0.f;
        wbuf[i] = v;
    }

    // gather x into bufA: feat then xyz-diff
    {
        const int k = t >> 3, f = t & 7;
        const int p = gi[k];
        const float* fr = feat + ((size_t)b * NPT + p) * 64 + f * 8;
        const float4 a0 = *(const float4*)fr;
        const float4 a1 = *(const float4*)(fr + 4);
        *(float4*)(bufA + k * 68 + f * 8)     = a0;
        *(float4*)(bufA + k * 68 + f * 8 + 4) = a1;
        if (f == 0) {
            const float qx = newxyz[grp * 3 + 0];
            const float qy = newxyz[grp * 3 + 1];
            const float qz = newxyz[grp * 3 + 2];
            const float* xp = xyz + ((size_t)b * NPT + p) * 3;
            bufA[k * 68 + 64] = xp[0] - qx;
            bufA[k * 68 + 65] = xp[1] - qy;
            bufA[k * 68 + 66] = xp[2] - qz;
            bufA[k * 68 + 67] = 0.f;
        }
    }
    __syncthreads();

    mlp_layer<4>(bufA, wbuf, sc, bi, bufB, 17, t);
    __syncthreads();

    for (int i = t; i < 64 * 68; i += 256) {
        const int o = i / 68, c = i - o * 68;
        wbuf[i] = (c < 64) ? w1[o * 64 + c] : 0.f;
    }
    __syncthreads();

    mlp_layer<4>(bufB, wbuf, sc + 64, bi + 64, bufA, 16, t);
    __syncthreads();

    for (int i = t; i < 128 * 68; i += 256) {
        const int o = i / 68, c = i - o * 68;
        wbuf[i] = (c < 64) ? w2[o * 64 + c] : 0.f;
    }
    __syncthreads();

    mlp_layer2(bufA, wbuf, sc + 128, bi + 128, out, b, s, t);
}

// ---------------------------------------------------------------------------
extern "C" void kernel_launch(void* const* d_in, const int* in_sizes, int n_in,
                              void* d_out, int out_size, void* d_ws, size_t ws_size,
                              hipStream_t stream)
{
    const float* xyz  = (const float*)d_in[0];
    const float* feat = (const float*)d_in[1];
    const float* w0 = (const float*)d_in[2];
    const float* g0 = (const float*)d_in[3];
    const float* b0 = (const float*)d_in[4];
    const float* m0 = (const float*)d_in[5];
    const float* v0 = (const float*)d_in[6];
    const float* w1 = (const float*)d_in[7];
    const float* g1 = (const float*)d_in[8];
    const float* b1 = (const float*)d_in[9];
    const float* m1 = (const float*)d_in[10];
    const float* v1 = (const float*)d_in[11];
    const float* w2 = (const float*)d_in[12];
    const float* g2 = (const float*)d_in[13];
    const float* b2 = (const float*)d_in[14];
    const float* m2 = (const float*)d_in[15];
    const float* v2 = (const float*)d_in[16];

    float* out      = (float*)d_out;
    float* new_xyz  = out;                      // 8*512*3 = 12288 floats
    float* out_feat = out + BATCH * NQ * 3;     // 8*128*512 floats

    // workspace layout
    int*   gidx  = (int*)d_ws;                                  // 524288 B
    float* sxp   = (float*)((char*)d_ws + 524288);              // 512 KB
    float* syp   = sxp + BATCH * NPT;                           // 512 KB
    float* szp   = syp + BATCH * NPT;                           // 512 KB
    int*   sorig = (int*)(szp + BATCH * NPT);                   // 512 KB

    sort_kernel<<<BATCH, 1024, 0, stream>>>(xyz, sxp, syp, szp, sorig);
    fps_kernel<<<BATCH, 1024, 0, stream>>>(xyz, sxp, syp, szp, sorig, new_xyz);
    bq_kernel<<<(BATCH * NQ * 64) / 256, 256, 0, stream>>>(xyz, new_xyz, gidx);
    mlp_kernel<<<BATCH * NQ, 256, 0, stream>>>(xyz, feat, new_xyz, gidx,
                                               w0, g0, b0, m0, v0,
                                               w1, g1, b1, m1, v1,
                                               w2, g2, b2, m2, v2,
                                               out_feat);
}